// Round 10
// baseline (208.774 us; speedup 1.0000x reference)
//
#include <hip/hip_runtime.h>
#include <hip/hip_bf16.h>

// FeatureAdaption R10: R7's verified 16x16 kernel core (8-slot swizzle, 0
// conflicts) + R9's K-split(2) partials/reduces + 8-wave/512-thread blocks
// -> 4096 waves = 4 waves/SIMD (2x R9 occupancy). setprio around MFMA.
// conv1(256->256) -> conv2(256->72)=offsets -> deform conv v1 + ReLU.
// B=8, C=256, H=W=64, dg=4, K=9 taps, K_total=2304.

typedef __attribute__((ext_vector_type(8))) short bf16x8;
typedef __attribute__((ext_vector_type(4))) float f32x4;

static __device__ __forceinline__ ushort f2bf(float f) {
  __hip_bfloat16 h = __float2bfloat16(f);
  return *reinterpret_cast<ushort*>(&h);
}
static __device__ __forceinline__ float bf2f(ushort u) {
  union { uint u32; float f; } cv;
  cv.u32 = ((uint)u) << 16;
  return cv.f;
}

// ---------------- weight prep: swizzled tiles (R5/R7 verbatim, verified) ----
// Layout: [ti 36][co][p(8)][e(8)]; stored = orig[co][ ti*64 + (p ^ (co&7))*8 + e ]
// conv  : ti = kk*4 + chunk  (ci = chunk*64 + cc)
// deform: ti = g*9 + kk      (c = cc within group)
__global__ __launch_bounds__(256) void prep_weights(
    const float* __restrict__ w1, const float* __restrict__ w2,
    const float* __restrict__ wd,
    ushort* __restrict__ wt1s, ushort* __restrict__ wt2s,
    ushort* __restrict__ wtds) {
  const int N1 = 36 * 256 * 64;
  const int N2 = 36 * 80 * 64;
  const int N3 = 36 * 256 * 64;
  int total = N1 + N2 + N3;
  for (int i = blockIdx.x * 256 + threadIdx.x; i < total; i += gridDim.x * 256) {
    if (i < N1) {
      int e = i & 7, p = (i >> 3) & 7, co = (i >> 6) & 255, ti = i >> 14;
      int cc = ((p ^ (co & 7)) << 3) + e;
      int kk = ti >> 2, chunk = ti & 3;
      wt1s[i] = f2bf(w1[(co * 256 + chunk * 64 + cc) * 9 + kk]);
    } else if (i < N1 + N2) {
      int d = i - N1;
      int e = d & 7, p = (d >> 3) & 7;
      int r = d >> 6;
      int co = r % 80, ti = r / 80;
      int cc = ((p ^ (co & 7)) << 3) + e;
      int kk = ti >> 2, chunk = ti & 3;
      wt2s[d] = (co < 72) ? f2bf(w2[(co * 256 + chunk * 64 + cc) * 9 + kk])
                          : (ushort)0;
    } else {
      int d = i - N1 - N2;
      int e = d & 7, p = (d >> 3) & 7, co = (d >> 6) & 255, ti = d >> 14;
      int c = ((p ^ (co & 7)) << 3) + e;
      int g = ti / 9, kk = ti - g * 9;
      wtds[d] = f2bf(wd[(co * 256 + g * 64 + c) * 9 + kk]);
    }
  }
}

// ---------------- x -> channel-last grouped bf16 (verified R3-R9) ------------
__global__ __launch_bounds__(256) void transpose_x(
    const float* __restrict__ x, ushort* __restrict__ xt) {
  int id = blockIdx.x;
  int y = id & 63, bg = id >> 6;
  int c = threadIdx.x & 63, xi = threadIdx.x >> 6;
  const float* ip = x + (((size_t)bg) << 18) + ((size_t)c << 12) + y * 64;
  ushort* op = xt + (((size_t)bg) << 18) + (size_t)y * 4096 + c;
#pragma unroll
  for (int j = 0; j < 16; ++j) {
    int xx = xi * 16 + j;
    op[(size_t)xx * 64] = f2bf(ip[xx]);
  }
}

// ---------------- MFMA kernel v7: 8 waves, K-split(2), bf16 partials --------
// Grid 512 = 8b x 32hp x 2khalf [XCD swizzled -> one batch per XCD].
// Block: 512 thr / 8 waves; wave w owns px [w*16, w*16+16) of a 128px (2-row)
// tile; all CO_TILE=NFR*16 outputs (no A duplication within the khalf).
// Per khalf: 18 BK=64 tiles. B tile XOR-swizzled in LDS (q=co&7, verified 0
// conflicts R7), double-buffered, staged via linear global_load_lds from
// pre-swizzled source. A-path pipelined one tile ahead (offsets two ahead).
template <int MODE, int NFR, bool CHLAST>
__global__ __launch_bounds__(512, 4) void fa_mfma8(
    const ushort* __restrict__ inT,  // [bg][4096 px][64 c] bf16
    const float* __restrict__ off,   // [B][72][64][64] f32 (MODE 1)
    const char* __restrict__ wBs,    // swizzled tiles [36][CO_TILE*128 bytes]
    ushort* __restrict__ parA,       // partial khalf 0 (bf16)
    ushort* __restrict__ parB,       // partial khalf 1 (bf16)
    int co_write) {
  constexpr int CO_TILE = NFR * 16;
  constexpr int TILE_B = CO_TILE * 128;            // bytes per K-tile
  constexpr int NCALLS = (TILE_B + 8191) / 8192;   // 16B x 512thr per call
  constexpr int NRN = (MODE == 1) ? 8 : 2;
  __shared__ __align__(16) ushort Blds[2][NCALLS * 4096];

  int id = blockIdx.x;
  int id2 = (id & 7) * 64 + (id >> 3);             // XCD swizzle (512 = 8*64)
  int khalf = id2 & 1;
  int rest = id2 >> 1;                             // [0,256)
  int hp = rest & 31, b = rest >> 5;               // hp [0,32), b [0,8)
  int t = threadIdx.x;
  int wv = t >> 6, lane = t & 63;
  int ml = lane & 15, kc = lane >> 4;
  int ml7 = ml & 7;
  ushort* par = khalf ? parB : parA;

  auto stage = [&](int tg, int bufsel) {
#pragma unroll
    for (int m = 0; m < NCALLS; ++m) {
      int d = (m * 512 + t) * 16;
      int ds = (d > TILE_B - 16) ? (TILE_B - 16) : d;  // clamp (tail call)
      const char* src = wBs + (size_t)tg * TILE_B + ds;
      ushort* dst = &Blds[bufsel][(m * 512 + t) * 8];
      __builtin_amdgcn_global_load_lds(
          (const __attribute__((address_space(1))) void*)src,
          (__attribute__((address_space(3))) void*)dst, 16, 0, 0);
    }
  };

  // this lane's pixel (A row)
  const int pxll = wv * 16 + ml;                   // [0,128)
  const int row = hp * 2 + (pxll >> 6);
  const int col = pxll & 63;

  const bf16x8 bz = {0, 0, 0, 0, 0, 0, 0, 0};
  bf16x8 aCur[2];
  bf16x8 rN[NRN];
  float wsv[4];
  float2 offA;

  // ---- MODE 0: direct conv A-path (R7 verbatim, tap decode on global ti) ----
  auto issueA0 = [&](int tg) {
    int kk = tg >> 2, chunk = tg & 3;
    int ky = kk / 3, kx = kk - ky * 3;
    int gy = row + ky - 1, gx = col + kx - 1;
    bool inb = (gy >= 0) & (gy < 64) & (gx >= 0) & (gx < 64);
    const ushort* p =
        inT + ((((size_t)(b * 4 + chunk) << 12) + gy * 64 + gx) << 6) + kc * 8;
    rN[0] = bz;
    rN[1] = bz;
    if (inb) {
      rN[0] = *(const bf16x8*)p;
      rN[1] = *(const bf16x8*)(p + 32);
    }
  };
  auto finishA0 = [&]() {
    aCur[0] = rN[0];
    aCur[1] = rN[1];
  };

  // ---- MODE 1: deform A-path (R7 verbatim) ----
  auto loadOff = [&](int tg) {
    int g = tg / 9, kk = tg - 9 * (tg / 9);
    int ch = g * 18 + kk * 2;
    const float* offp = off + (((size_t)b * 72 + ch) << 12) + row * 64 + col;
    offA.x = offp[0];
    offA.y = offp[4096];
  };
  auto issueA1 = [&](int tg) {
    int g = tg / 9, kk = tg - 9 * (tg / 9);
    int ky = kk / 3, kx = kk - ky * 3;
    const ushort* base = inT + (((size_t)(b * 4 + g)) << 18) + kc * 8;
    float py = (float)(row + ky - 1) + offA.x;
    float pxf = (float)(col + kx - 1) + offA.y;
    float y0f = floorf(py), x0f = floorf(pxf);
    float wy1 = py - y0f, wx1 = pxf - x0f;
    float wy0 = 1.f - wy1, wx0 = 1.f - wx1;
    int y0 = (int)y0f, x0i = (int)x0f;
    int y1 = y0 + 1, x1i = x0i + 1;
    bool vy0 = (y0 >= 0) & (y0 < 64);
    bool vy1 = (y1 >= 0) & (y1 < 64);
    bool vx0 = (x0i >= 0) & (x0i < 64);
    bool vx1 = (x1i >= 0) & (x1i < 64);
    wsv[0] = (vy0 & vx0) ? wy0 * wx0 : 0.f;
    wsv[1] = (vy0 & vx1) ? wy0 * wx1 : 0.f;
    wsv[2] = (vy1 & vx0) ? wy1 * wx0 : 0.f;
    wsv[3] = (vy1 & vx1) ? wy1 * wx1 : 0.f;
    int yc0 = min(max(y0, 0), 63), yc1 = min(max(y1, 0), 63);
    int xc0 = min(max(x0i, 0), 63), xc1 = min(max(x1i, 0), 63);
    const ushort* p00 = base + ((yc0 * 64 + xc0) << 6);
    const ushort* p01 = base + ((yc0 * 64 + xc1) << 6);
    const ushort* p10 = base + ((yc1 * 64 + xc0) << 6);
    const ushort* p11 = base + ((yc1 * 64 + xc1) << 6);
    rN[0] = *(const bf16x8*)p00;
    rN[1] = *(const bf16x8*)(p00 + 32);
    rN[2] = *(const bf16x8*)p01;
    rN[3] = *(const bf16x8*)(p01 + 32);
    rN[4] = *(const bf16x8*)p10;
    rN[5] = *(const bf16x8*)(p10 + 32);
    rN[6] = *(const bf16x8*)p11;
    rN[7] = *(const bf16x8*)(p11 + 32);
  };
  auto finishA1 = [&]() {
    float w00 = wsv[0], w01 = wsv[1], w10 = wsv[2], w11 = wsv[3];
#pragma unroll
    for (int ks = 0; ks < 2; ++ks) {
      bf16x8 q00 = rN[0 + ks], q01 = rN[2 + ks];
      bf16x8 q10 = rN[4 + ks], q11 = rN[6 + ks];
      bf16x8 av;
#pragma unroll
      for (int jj = 0; jj < 4; ++jj) {
        float v0 = w00 * bf2f((ushort)q00[2 * jj]) + w01 * bf2f((ushort)q01[2 * jj]) +
                   w10 * bf2f((ushort)q10[2 * jj]) + w11 * bf2f((ushort)q11[2 * jj]);
        float v1 = w00 * bf2f((ushort)q00[2 * jj + 1]) + w01 * bf2f((ushort)q01[2 * jj + 1]) +
                   w10 * bf2f((ushort)q10[2 * jj + 1]) + w11 * bf2f((ushort)q11[2 * jj + 1]);
        av[2 * jj] = (short)f2bf(v0);
        av[2 * jj + 1] = (short)f2bf(v1);
      }
      aCur[ks] = av;
    }
  };

  f32x4 acc[NFR];
#pragma unroll
  for (int j = 0; j < NFR; ++j) acc[j] = (f32x4){0.f, 0.f, 0.f, 0.f};

  const int t0 = khalf * 18;

  // prologue
  if (MODE == 1) {
    loadOff(t0);
    issueA1(t0);
    loadOff(t0 + 1);
    finishA1();
  } else {
    issueA0(t0);
    finishA0();
  }
  stage(t0, 0);
  __syncthreads();

  for (int tloc = 0; tloc < 18; ++tloc) {
    int tg = t0 + tloc;
    int cur = tloc & 1;
    if (tloc < 17) {
      stage(tg + 1, cur ^ 1);
      if (MODE == 1) issueA1(tg + 1); else issueA0(tg + 1);
    }
    if (MODE == 1 && tloc < 16) loadOff(tg + 2);

    __builtin_amdgcn_s_setprio(1);
#pragma unroll
    for (int ks = 0; ks < 2; ++ks) {
      int sw = (((ks * 4 + kc) ^ ml7) << 3);       // swizzled 16B slot
      bf16x8 bq[NFR];
#pragma unroll
      for (int nf = 0; nf < NFR; ++nf)
        bq[nf] = *(const bf16x8*)&Blds[cur][(nf * 16 + ml) * 64 + sw];
#pragma unroll
      for (int nf = 0; nf < NFR; ++nf)
        acc[nf] = __builtin_amdgcn_mfma_f32_16x16x32_bf16(
            aCur[ks], bq[nf], acc[nf], 0, 0, 0);
    }
    __builtin_amdgcn_s_setprio(0);

    if (tloc < 17) { if (MODE == 1) finishA1(); else finishA0(); }
    __syncthreads();
  }

  // epilogue: write bf16 partials. D col = lane&15 (co), row = rq*4+ri (px).
  int rq = lane >> 4;
#pragma unroll
  for (int nf = 0; nf < NFR; ++nf) {
    int cog = nf * 16 + ml;
    if (cog < co_write) {
#pragma unroll
      for (int ri = 0; ri < 4; ++ri) {
        int pix = hp * 128 + wv * 16 + rq * 4 + ri;
        ushort v = f2bf(acc[nf][ri]);
        if (CHLAST) {
          par[((((size_t)(b * 4 + (cog >> 6)) << 12) + pix) << 6) + (cog & 63)] = v;
        } else {
          par[(((size_t)b * co_write + cog) << 12) + pix] = v;
        }
      }
    }
  }
}

// ---------------- reduce kernels (R9 verbatim, verified) ----------------
__global__ __launch_bounds__(256) void reduce_c1(
    const ushort* __restrict__ p0, const ushort* __restrict__ p1,
    const float* __restrict__ bias, ushort* __restrict__ t1) {
  const int N8 = (8 * 4 * 4096 * 64) / 8;
  for (int i = blockIdx.x * 256 + threadIdx.x; i < N8; i += gridDim.x * 256) {
    size_t base = (size_t)i * 8;
    bf16x8 a = *(const bf16x8*)(p0 + base);
    bf16x8 c = *(const bf16x8*)(p1 + base);
    int c0 = (int)(base & 63);
    int g = (int)((base >> 18) & 3);
    bf16x8 o;
#pragma unroll
    for (int j = 0; j < 8; ++j) {
      float v = bf2f((ushort)a[j]) + bf2f((ushort)c[j]) + bias[g * 64 + c0 + j];
      o[j] = (short)f2bf(v);
    }
    *(bf16x8*)(t1 + base) = o;
  }
}

__global__ __launch_bounds__(256) void reduce_c2(
    const ushort* __restrict__ p0, const ushort* __restrict__ p1,
    const float* __restrict__ bias, float* __restrict__ out) {
  const int N8 = (8 * 72 * 4096) / 8;
  for (int i = blockIdx.x * 256 + threadIdx.x; i < N8; i += gridDim.x * 256) {
    size_t base = (size_t)i * 8;
    bf16x8 a = *(const bf16x8*)(p0 + base);
    bf16x8 c = *(const bf16x8*)(p1 + base);
    int co = (int)((base >> 12) % 72);
    float bv = bias[co];
    float4 o0, o1;
    o0.x = bf2f((ushort)a[0]) + bf2f((ushort)c[0]) + bv;
    o0.y = bf2f((ushort)a[1]) + bf2f((ushort)c[1]) + bv;
    o0.z = bf2f((ushort)a[2]) + bf2f((ushort)c[2]) + bv;
    o0.w = bf2f((ushort)a[3]) + bf2f((ushort)c[3]) + bv;
    o1.x = bf2f((ushort)a[4]) + bf2f((ushort)c[4]) + bv;
    o1.y = bf2f((ushort)a[5]) + bf2f((ushort)c[5]) + bv;
    o1.z = bf2f((ushort)a[6]) + bf2f((ushort)c[6]) + bv;
    o1.w = bf2f((ushort)a[7]) + bf2f((ushort)c[7]) + bv;
    *(float4*)(out + base) = o0;
    *(float4*)(out + base + 4) = o1;
  }
}

__global__ __launch_bounds__(256) void reduce_df(
    const ushort* __restrict__ p0, const ushort* __restrict__ p1,
    float* __restrict__ out) {
  __shared__ float ts[64][65];
  int bid = blockIdx.x;                  // 2048 = 8b * 4cq * 64pt
  int pt = bid & 63, cq = (bid >> 6) & 3, b = bid >> 8;
  int t = threadIdx.x;
  int c = t & 63, ty = t >> 6;
  size_t inbase = (((size_t)(b * 4 + cq) << 12) + pt * 64) << 6;
#pragma unroll 4
  for (int s = 0; s < 16; ++s) {
    int pxi = ty * 16 + s;
    size_t idx = inbase + ((size_t)pxi << 6) + c;
    float v = bf2f(p0[idx]) + bf2f(p1[idx]);
    ts[c][pxi] = fmaxf(v, 0.f);
  }
  __syncthreads();
  int px = t & 63;
#pragma unroll 4
  for (int s = 0; s < 16; ++s) {
    int coi = ty * 16 + s;
    out[(((size_t)b * 256 + cq * 64 + coi) << 12) + pt * 64 + px] = ts[coi][px];
  }
}

extern "C" void kernel_launch(void* const* d_in, const int* in_sizes, int n_in,
                              void* d_out, int out_size, void* d_ws, size_t ws_size,
                              hipStream_t stream) {
  const float* x  = (const float*)d_in[0];
  const float* w1 = (const float*)d_in[1];
  const float* b1 = (const float*)d_in[2];
  const float* w2 = (const float*)d_in[3];
  const float* b2 = (const float*)d_in[4];
  const float* wd = (const float*)d_in[5];

  char* wsb = (char*)d_ws;
  float*  off_buf = (float*)wsb;                    //  9,437,184 B
  ushort* xt      = (ushort*)(wsb + 9437184);       // 16,777,216 B
  ushort* wt1s    = (ushort*)(wsb + 26214400);      //  1,179,648 B
  ushort* wt2s    = (ushort*)(wsb + 27394048);      //    368,640 B
  ushort* wtds    = (ushort*)(wsb + 27762688);      //  1,179,648 B
  ushort* par0    = (ushort*)(wsb + 28942336);      // 16,777,216 B
  ushort* par1    = (ushort*)(wsb + 45719552);      // 16,777,216 B -> 62.5 MB

  prep_weights<<<2048, 256, 0, stream>>>(w1, w2, wd, wt1s, wt2s, wtds);
  transpose_x<<<2048, 256, 0, stream>>>(x, xt);

  ushort* t1 = (ushort*)d_out;   // bf16 chlast t1 lives in d_out until deform

  // conv1: xt -> partials (chlast), CO_TILE=256, 512 blocks x 512 thr
  fa_mfma8<0, 16, true><<<512, 512, 0, stream>>>(
      xt, nullptr, (const char*)wt1s, par0, par1, 256);
  reduce_c1<<<2048, 256, 0, stream>>>(par0, par1, b1, t1);

  // conv2: t1 -> partials (planar, co<72), CO_TILE=80
  fa_mfma8<0, 5, false><<<512, 512, 0, stream>>>(
      t1, nullptr, (const char*)wt2s, par0, par1, 72);
  reduce_c2<<<1024, 256, 0, stream>>>(par0, par1, b2, off_buf);

  // deform: xt + offsets -> partials (chlast), CO_TILE=256
  fa_mfma8<1, 16, true><<<512, 512, 0, stream>>>(
      xt, off_buf, (const char*)wtds, par0, par1, 256);
  reduce_df<<<2048, 256, 0, stream>>>(par0, par1, (float*)d_out);
}